// Round 9
// baseline (478.092 us; speedup 1.0000x reference)
//
#include <hip/hip_runtime.h>
#include <math.h>

#define DIN 256
#define HDIM 128
#define NCRIT 10

typedef __bf16 bf16;
typedef bf16 bf16x8 __attribute__((ext_vector_type(8)));
typedef float f32x4 __attribute__((ext_vector_type(4)));

static inline size_t alignup(size_t x, size_t a) { return (x + a - 1) & ~(a - 1); }

__device__ inline float bflo(unsigned v) { return __uint_as_float(v << 16); }
__device__ inline float bfhi(unsigned v) { return __uint_as_float(v & 0xffff0000u); }

__device__ inline bf16x8 cvt8(float4 v0, float4 v1) {
    bf16x8 w;
    w[0] = (bf16)v0.x; w[1] = (bf16)v0.y; w[2] = (bf16)v0.z; w[3] = (bf16)v0.w;
    w[4] = (bf16)v1.x; w[5] = (bf16)v1.y; w[6] = (bf16)v1.z; w[7] = (bf16)v1.w;
    return w;
}

__device__ inline void gl_lds16(const void* g, void* l) {
    __builtin_amdgcn_global_load_lds(
        (const __attribute__((address_space(1))) unsigned*)g,
        (__attribute__((address_space(3))) unsigned*)l, 16, 0, 0);
}

// ---------- CSR build (single atomic pass, scalar) ----------
__global__ void k_hist(const int* __restrict__ dst, int E, int* __restrict__ cnt,
                       int* __restrict__ epos) {
    int i = blockIdx.x * 256 + threadIdx.x;
    if (i < E) epos[i] = atomicAdd(&cnt[dst[i]], 1);
}

// ---------- alloc (wave scan + atomic base) fused with wconv ----------
__global__ void k_allocw(const int* __restrict__ cnt, int n, int* __restrict__ off,
                         int* __restrict__ total, int nAllocBlocks,
                         const float* __restrict__ Wl, const float* __restrict__ Wr,
                         const float* __restrict__ Wres, bf16* __restrict__ Wcat) {
    if ((int)blockIdx.x < nAllocBlocks) {
        int i = blockIdx.x * 256 + threadIdx.x;
        int lane = threadIdx.x & 63;
        int v = (i < n) ? cnt[i] : 0;
        int s = v;
        #pragma unroll
        for (int d = 1; d < 64; d <<= 1) {
            int t = __shfl_up(s, d, 64);
            if (lane >= d) s += t;
        }
        int excl = s - v;
        int wtot = __shfl(s, 63, 64);
        int base = 0;
        if (lane == 63) base = atomicAdd(total, wtot);
        base = __shfl(base, 63, 64);
        if (i < n) off[i] = base + excl;
    } else {
        int i = (blockIdx.x - nAllocBlocks) * 256 + threadIdx.x;
        int base = i * 4;
        if (base >= 384 * 256) return;
        int r = base >> 8;
        int c = base & 255;
        const float* W = (r < 128) ? Wl : ((r < 256) ? Wr : Wres);
        float4 v = *(const float4*)&W[(size_t)(r & 127) * 256 + c];
        bf16* o = &Wcat[base];
        o[0] = (bf16)v.x; o[1] = (bf16)v.y; o[2] = (bf16)v.z; o[3] = (bf16)v.w;
    }
}

__global__ void k_scatter(const int* __restrict__ src, const int* __restrict__ dst,
                          const int* __restrict__ epos, int E,
                          const int* __restrict__ off, int* __restrict__ sidx) {
    int i = blockIdx.x * 256 + threadIdx.x;
    if (i < E) sidx[off[dst[i]] + epos[i]] = src[i];
}

// ---------- MFMA GEMM: [y|z] = x @ Wcat^T, BM=64 BN=384 BK=32, dbuf + global_load_lds ----------
// y stored PANEL-MAJOR: yp[p][node][16 cols] (32B per node-panel), p = 0..7
__global__ __launch_bounds__(256) void k_gemm(const float* __restrict__ x,
                                              const bf16* __restrict__ Wcat, int n,
                                              bf16* __restrict__ yp, bf16* __restrict__ z) {
    __shared__ __align__(16) char smem[57344];
    int t = threadIdx.x;
    int wv = t >> 6, lane = t & 63;
    int node0 = blockIdx.x * 64;

    f32x4 acc[4][6] = {};

    int a_r = t >> 2, a_kq = t & 3;
    int a_gr = node0 + a_r;
    const float* a_src = &x[(size_t)a_gr * DIN + a_kq * 8];
    int a_woff = a_kq * 1024 + ((a_r ^ (a_kq << 1)) << 4);

    int gOff[6];
    const char* wcb = (const char*)Wcat;
    #pragma unroll
    for (int i = 0; i < 6; i++) {
        int LL = i * 256 + t;
        int kg = LL / 384;
        int c = LL - kg * 384;
        gOff[i] = c * 512 + kg * 16;
    }

    int f_kg = lane >> 4, f_l15 = lane & 15;
    int aRd[4];
    #pragma unroll
    for (int m = 0; m < 4; m++) {
        int r = m * 16 + f_l15;
        aRd[m] = f_kg * 1024 + ((r ^ (f_kg << 1)) << 4);
    }
    int bRd[6];
    #pragma unroll
    for (int nn = 0; nn < 6; nn++) {
        int c = wv * 96 + nn * 16 + f_l15;
        bRd[nn] = f_kg * 6144 + c * 16;
    }

    {
        float4 v0, v1;
        if (a_gr < n) { v0 = *(const float4*)a_src; v1 = *(const float4*)(a_src + 4); }
        else { v0 = make_float4(0, 0, 0, 0); v1 = v0; }
        *(bf16x8*)(smem + 49152 + a_woff) = cvt8(v0, v1);
        #pragma unroll
        for (int i = 0; i < 6; i++)
            gl_lds16(wcb + gOff[i], smem + i * 4096 + wv * 1024);
    }
    __syncthreads();

    #pragma unroll 2
    for (int s = 0; s < 8; ++s) {
        int cur = s & 1;
        float4 v0, v1;
        if (s < 7) {
            if (a_gr < n) {
                v0 = *(const float4*)(a_src + (s + 1) * 32);
                v1 = *(const float4*)(a_src + (s + 1) * 32 + 4);
            } else { v0 = make_float4(0, 0, 0, 0); v1 = v0; }
            #pragma unroll
            for (int i = 0; i < 6; i++)
                gl_lds16(wcb + gOff[i] + (s + 1) * 64,
                         smem + (cur ^ 1) * 24576 + i * 4096 + wv * 1024);
        }
        bf16x8 afr[4], bfr[6];
        #pragma unroll
        for (int m = 0; m < 4; m++)
            afr[m] = *(const bf16x8*)(smem + 49152 + cur * 4096 + aRd[m]);
        #pragma unroll
        for (int nn = 0; nn < 6; nn++)
            bfr[nn] = *(const bf16x8*)(smem + cur * 24576 + bRd[nn]);
        __builtin_amdgcn_s_setprio(1);
        #pragma unroll
        for (int m = 0; m < 4; m++)
            #pragma unroll
            for (int nn = 0; nn < 6; nn++)
                acc[m][nn] = __builtin_amdgcn_mfma_f32_16x16x32_bf16(
                    afr[m], bfr[nn], acc[m][nn], 0, 0, 0);
        __builtin_amdgcn_s_setprio(0);
        if (s < 7)
            *(bf16x8*)(smem + 49152 + (cur ^ 1) * 4096 + a_woff) = cvt8(v0, v1);
        __syncthreads();
    }

    bf16* Cs = (bf16*)smem;
    #pragma unroll
    for (int m = 0; m < 4; m++) {
        #pragma unroll
        for (int nn = 0; nn < 6; nn++) {
            int col = wv * 96 + nn * 16 + f_l15;
            int r0 = m * 16 + (f_kg << 2);
            #pragma unroll
            for (int j = 0; j < 4; j++)
                Cs[(r0 + j) * 392 + col] = (bf16)acc[m][nn][j];
        }
    }
    __syncthreads();

    // y panel-major store: thread -> (panel pp = t&7, rows t>>3 and t>>3+32)
    {
        int pp = t & 7, rb = t >> 3;
        #pragma unroll
        for (int hh = 0; hh < 2; hh++) {
            int r = rb + hh * 32;
            int gr = node0 + r;
            if (gr < n) {
                char* dstp = (char*)yp + ((size_t)pp * n + gr) * 32;
                uint4 w0 = *(const uint4*)&Cs[r * 392 + pp * 16];
                uint4 w1 = *(const uint4*)&Cs[r * 392 + pp * 16 + 8];
                *(uint4*)dstp = w0;
                *(uint4*)(dstp + 16) = w1;
            }
        }
    }
    // z store unchanged: [node][256]
    {
        int r = t >> 2;
        int gr = node0 + r;
        if (gr < n) {
            #pragma unroll
            for (int u = 0; u < 8; u++) {
                int c = (t & 3) * 8 + u * 32;
                uint4 v = *(const uint4*)&Cs[r * 392 + 128 + c];
                *(uint4*)&z[(size_t)gr * 2 * HDIM + c] = v;
            }
        }
    }
}

// ---------- panel gather: grid (ceil(N/4), 8 panels), one wave per node ----------
__global__ __launch_bounds__(256) void k_gpanel(
    const bf16* __restrict__ yp, const int* __restrict__ off, const int* __restrict__ cnt,
    const int* __restrict__ sidx, int n, bf16* __restrict__ aggy)
{
    int p = blockIdx.y;
    int node = blockIdx.x * 4 + (threadIdx.x >> 6);
    if (node >= n) return;
    int lane = threadIdx.x & 63;
    int g = lane >> 2, s = lane & 3;       // 16 edge-groups x 4 col-lanes (8B each)

    const char* pb = (const char*)yp + (size_t)p * n * 32 + s * 8;
    int beg = off[node], len = cnt[node];
    const int* sp = sidx + beg;

    float a0 = 0.f, a1 = 0.f, a2 = 0.f, a3 = 0.f;
    for (int e = 0; e < len; e += 16) {
        int slot = e + g;
        int idx = sp[slot < len ? slot : len - 1];
        uint2 v = *(const uint2*)(pb + (size_t)(unsigned)idx * 32);
        if (slot < len) {
            a0 += bflo(v.x); a1 += bfhi(v.x);
            a2 += bflo(v.y); a3 += bfhi(v.y);
        }
    }
    #pragma unroll
    for (int d = 4; d < 64; d <<= 1) {
        a0 += __shfl_xor(a0, d, 64);
        a1 += __shfl_xor(a1, d, 64);
        a2 += __shfl_xor(a2, d, 64);
        a3 += __shfl_xor(a3, d, 64);
    }
    if (g == 0) {
        float inv = 1.f / fmaxf((float)len, 1.f);
        bf16 o[4] = {(bf16)(a0 * inv), (bf16)(a1 * inv), (bf16)(a2 * inv), (bf16)(a3 * inv)};
        *(uint2*)((char*)aggy + (size_t)node * 256 + p * 32 + s * 8) = *(const uint2*)o;
    }
}

// ---------- epilogue: one wave per node (streamed) ----------
__global__ __launch_bounds__(256) void k_epi(
    const bf16* __restrict__ aggy, const bf16* __restrict__ z,
    const float* __restrict__ bl, const float* __restrict__ bres,
    const float* __restrict__ wscore, const float* __restrict__ bscore,
    const float* __restrict__ wcrit, const float* __restrict__ bcrit,
    const float* __restrict__ rrs, const float* __restrict__ palpha,
    int n, float* __restrict__ outF, float* __restrict__ outL)
{
    __shared__ bf16 wsb[11 * 128];
    int t = threadIdx.x;
    for (int i = t; i < 11 * 128; i += 256) {
        int q = i >> 7, c = i & 127;
        wsb[i] = (bf16)((q == 0) ? wscore[c] : wcrit[(size_t)(q - 1) * HDIM + c]);
    }
    __syncthreads();

    int node = blockIdx.x * 4 + (t >> 6);
    if (node >= n) return;
    int lane = t & 63, r2 = lane >> 5, c32 = lane & 31;

    uint2 av = *(const uint2*)((const char*)aggy + (size_t)node * 256 + c32 * 8);
    uint2 zr = *(const uint2*)&z[(size_t)node * 2 * HDIM + c32 * 4];
    uint2 zs = *(const uint2*)&z[(size_t)node * 2 * HDIM + HDIM + c32 * 4];
    float4 blv = *(const float4*)&bl[c32 * 4];
    float4 brv = *(const float4*)&bres[c32 * 4];

    float h0 = fmaxf(bflo(av.x) + blv.x + bflo(zr.x), 0.f) + bflo(zs.x) + brv.x;
    float h1 = fmaxf(bfhi(av.x) + blv.y + bfhi(zr.x), 0.f) + bfhi(zs.x) + brv.y;
    float h2 = fmaxf(bflo(av.y) + blv.z + bflo(zr.y), 0.f) + bflo(zs.y) + brv.z;
    float h3 = fmaxf(bfhi(av.y) + blv.w + bfhi(zr.y), 0.f) + bfhi(zs.y) + brv.w;

    // split epilogue: half r2=0 handles q=0..5, half r2=1 handles q=6..10
    float p[6];
    #pragma unroll
    for (int qq = 0; qq < 6; qq++) {
        int q = r2 * 6 + qq;
        float s = 0.f;
        if (q < 11) {
            uint2 w = *(const uint2*)&wsb[q * 128 + c32 * 4];
            s = h0 * bflo(w.x) + h1 * bfhi(w.x) + h2 * bflo(w.y) + h3 * bfhi(w.y);
        }
        #pragma unroll
        for (int d = 1; d < 32; d <<= 1)
            s += __shfl_xor(s, d, 64);
        p[qq] = s;
    }
    if ((lane & 31) == 0) {
        if (r2 == 0) {
            float al = palpha[0];
            float aa = 1.f / (1.f + expf(-al));
            outF[node] = aa * rrs[node] + (1.f - aa) * (p[0] + bscore[0]);
            #pragma unroll
            for (int qq = 1; qq < 6; qq++)
                outL[(size_t)node * NCRIT + qq - 1] = p[qq] + bcrit[qq - 1];
        } else {
            #pragma unroll
            for (int qq = 0; qq < 5; qq++)
                outL[(size_t)node * NCRIT + 5 + qq] = p[qq] + bcrit[5 + qq];
        }
    }
}

extern "C" void kernel_launch(void* const* d_in, const int* in_sizes, int n_in,
                              void* d_out, int out_size, void* d_ws, size_t ws_size,
                              hipStream_t stream) {
    const float* x      = (const float*)d_in[0];
    const int*   ei     = (const int*)d_in[1];
    const float* rrs    = (const float*)d_in[2];
    const float* Wl     = (const float*)d_in[3];
    const float* bl     = (const float*)d_in[4];
    const float* Wr     = (const float*)d_in[5];
    const float* Wres   = (const float*)d_in[6];
    const float* bres   = (const float*)d_in[7];
    const float* wscore = (const float*)d_in[8];
    const float* bscore = (const float*)d_in[9];
    const float* wcrit  = (const float*)d_in[10];
    const float* bcrit  = (const float*)d_in[11];
    const float* alpha  = (const float*)d_in[12];

    int N = in_sizes[0] / DIN;
    int E = in_sizes[1] / 2;
    const int* srcv = ei;
    const int* dstv = ei + E;

    char* p = (char*)d_ws;
    size_t cntPad = alignup((size_t)N * 4, 256);
    int* cnt   = (int*)p; p += cntPad;
    int* total = (int*)p; p += 256;
    int* off   = (int*)p; p += alignup((size_t)N * 4, 256);
    int* sidx  = (int*)p; p += alignup((size_t)E * 4, 256);
    bf16* Wcat = (bf16*)p; p += alignup((size_t)384 * DIN * 2, 256);
    bf16* yp   = (bf16*)p; p += alignup((size_t)N * HDIM * 2, 256);
    bf16* z    = (bf16*)p; p += alignup((size_t)N * 2 * HDIM * 2, 256);
    bf16* aggy = (bf16*)p; p += alignup((size_t)N * HDIM * 2, 256);
    int* epos  = (int*)aggy;   // aggy region reused: epos dead before aggy written

    // single memset covers cnt + total (adjacent)
    hipMemsetAsync(cnt, 0, cntPad + 256, stream);

    k_hist<<<(E + 255) / 256, 256, 0, stream>>>(dstv, E, cnt, epos);
    int nAllocBlocks = (N + 255) / 256;
    k_allocw<<<nAllocBlocks + 96, 256, 0, stream>>>(cnt, N, off, total, nAllocBlocks,
                                                    Wl, Wr, Wres, Wcat);
    k_scatter<<<(E + 255) / 256, 256, 0, stream>>>(srcv, dstv, epos, E, off, sidx);

    k_gemm<<<(N + 63) / 64, 256, 0, stream>>>(x, Wcat, N, yp, z);

    dim3 pg((N + 3) / 4, 8);
    k_gpanel<<<pg, 256, 0, stream>>>(yp, off, cnt, sidx, N, aggy);

    float* outF = (float*)d_out;
    float* outL = outF + N;
    k_epi<<<(N + 3) / 4, 256, 0, stream>>>(aggy, z, bl, bres, wscore, bscore,
                                           wcrit, bcrit, rrs, alpha, N, outF, outL);
}

// Round 10
// 282.871 us; speedup vs baseline: 1.6901x; 1.6901x over previous
//
#include <hip/hip_runtime.h>
#include <math.h>

#define DIN 256
#define HDIM 128
#define NCRIT 10

typedef __bf16 bf16;
typedef bf16 bf16x8 __attribute__((ext_vector_type(8)));
typedef float f32x4 __attribute__((ext_vector_type(4)));

static inline size_t alignup(size_t x, size_t a) { return (x + a - 1) & ~(a - 1); }

__device__ inline float bflo(unsigned v) { return __uint_as_float(v << 16); }
__device__ inline float bfhi(unsigned v) { return __uint_as_float(v & 0xffff0000u); }

__device__ inline bf16x8 cvt8(float4 v0, float4 v1) {
    bf16x8 w;
    w[0] = (bf16)v0.x; w[1] = (bf16)v0.y; w[2] = (bf16)v0.z; w[3] = (bf16)v0.w;
    w[4] = (bf16)v1.x; w[5] = (bf16)v1.y; w[6] = (bf16)v1.z; w[7] = (bf16)v1.w;
    return w;
}

__device__ inline unsigned char f32_fp8(float f) {
    return (unsigned char)(__builtin_amdgcn_cvt_pk_fp8_f32(f, f, 0, false) & 0xFF);
}

__device__ inline void gl_lds16(const void* g, void* l) {
    __builtin_amdgcn_global_load_lds(
        (const __attribute__((address_space(1))) unsigned*)g,
        (__attribute__((address_space(3))) unsigned*)l, 16, 0, 0);
}

// ---------- CSR build (single atomic pass, scalar) ----------
__global__ void k_hist(const int* __restrict__ dst, int E, int* __restrict__ cnt,
                       int* __restrict__ epos) {
    int i = blockIdx.x * 256 + threadIdx.x;
    if (i < E) epos[i] = atomicAdd(&cnt[dst[i]], 1);
}

// ---------- alloc (wave scan + atomic base) fused with wconv ----------
__global__ void k_allocw(const int* __restrict__ cnt, int n, int* __restrict__ off,
                         int* __restrict__ total, int nAllocBlocks,
                         const float* __restrict__ Wl, const float* __restrict__ Wr,
                         const float* __restrict__ Wres, bf16* __restrict__ Wcat) {
    if ((int)blockIdx.x < nAllocBlocks) {
        int i = blockIdx.x * 256 + threadIdx.x;
        int lane = threadIdx.x & 63;
        int v = (i < n) ? cnt[i] : 0;
        int s = v;
        #pragma unroll
        for (int d = 1; d < 64; d <<= 1) {
            int t = __shfl_up(s, d, 64);
            if (lane >= d) s += t;
        }
        int excl = s - v;
        int wtot = __shfl(s, 63, 64);
        int base = 0;
        if (lane == 63) base = atomicAdd(total, wtot);
        base = __shfl(base, 63, 64);
        if (i < n) off[i] = base + excl;
    } else {
        int i = (blockIdx.x - nAllocBlocks) * 256 + threadIdx.x;
        int base = i * 4;
        if (base >= 384 * 256) return;
        int r = base >> 8;
        int c = base & 255;
        const float* W = (r < 128) ? Wl : ((r < 256) ? Wr : Wres);
        float4 v = *(const float4*)&W[(size_t)(r & 127) * 256 + c];
        bf16* o = &Wcat[base];
        o[0] = (bf16)v.x; o[1] = (bf16)v.y; o[2] = (bf16)v.z; o[3] = (bf16)v.w;
    }
}

__global__ void k_scatter(const int* __restrict__ src, const int* __restrict__ dst,
                          const int* __restrict__ epos, int E,
                          const int* __restrict__ off, int* __restrict__ sidx) {
    int i = blockIdx.x * 256 + threadIdx.x;
    if (i < E) sidx[off[dst[i]] + epos[i]] = src[i];
}

// ---------- MFMA GEMM: [y|z] = x @ Wcat^T, BM=64 BN=384 BK=32, dbuf + global_load_lds ----------
// y stored fp8 e4m3 [node][128]; z bf16 [node][256]
__global__ __launch_bounds__(256) void k_gemm(const float* __restrict__ x,
                                              const bf16* __restrict__ Wcat, int n,
                                              unsigned char* __restrict__ yq,
                                              bf16* __restrict__ z) {
    __shared__ __align__(16) char smem[57344];
    int t = threadIdx.x;
    int wv = t >> 6, lane = t & 63;
    int node0 = blockIdx.x * 64;

    f32x4 acc[4][6] = {};

    int a_r = t >> 2, a_kq = t & 3;
    int a_gr = node0 + a_r;
    const float* a_src = &x[(size_t)a_gr * DIN + a_kq * 8];
    int a_woff = a_kq * 1024 + ((a_r ^ (a_kq << 1)) << 4);

    int gOff[6];
    const char* wcb = (const char*)Wcat;
    #pragma unroll
    for (int i = 0; i < 6; i++) {
        int LL = i * 256 + t;
        int kg = LL / 384;
        int c = LL - kg * 384;
        gOff[i] = c * 512 + kg * 16;
    }

    int f_kg = lane >> 4, f_l15 = lane & 15;
    int aRd[4];
    #pragma unroll
    for (int m = 0; m < 4; m++) {
        int r = m * 16 + f_l15;
        aRd[m] = f_kg * 1024 + ((r ^ (f_kg << 1)) << 4);
    }
    int bRd[6];
    #pragma unroll
    for (int nn = 0; nn < 6; nn++) {
        int c = wv * 96 + nn * 16 + f_l15;
        bRd[nn] = f_kg * 6144 + c * 16;
    }

    {
        float4 v0, v1;
        if (a_gr < n) { v0 = *(const float4*)a_src; v1 = *(const float4*)(a_src + 4); }
        else { v0 = make_float4(0, 0, 0, 0); v1 = v0; }
        *(bf16x8*)(smem + 49152 + a_woff) = cvt8(v0, v1);
        #pragma unroll
        for (int i = 0; i < 6; i++)
            gl_lds16(wcb + gOff[i], smem + i * 4096 + wv * 1024);
    }
    __syncthreads();

    #pragma unroll 2
    for (int s = 0; s < 8; ++s) {
        int cur = s & 1;
        float4 v0, v1;
        if (s < 7) {
            if (a_gr < n) {
                v0 = *(const float4*)(a_src + (s + 1) * 32);
                v1 = *(const float4*)(a_src + (s + 1) * 32 + 4);
            } else { v0 = make_float4(0, 0, 0, 0); v1 = v0; }
            #pragma unroll
            for (int i = 0; i < 6; i++)
                gl_lds16(wcb + gOff[i] + (s + 1) * 64,
                         smem + (cur ^ 1) * 24576 + i * 4096 + wv * 1024);
        }
        bf16x8 afr[4], bfr[6];
        #pragma unroll
        for (int m = 0; m < 4; m++)
            afr[m] = *(const bf16x8*)(smem + 49152 + cur * 4096 + aRd[m]);
        #pragma unroll
        for (int nn = 0; nn < 6; nn++)
            bfr[nn] = *(const bf16x8*)(smem + cur * 24576 + bRd[nn]);
        __builtin_amdgcn_s_setprio(1);
        #pragma unroll
        for (int m = 0; m < 4; m++)
            #pragma unroll
            for (int nn = 0; nn < 6; nn++)
                acc[m][nn] = __builtin_amdgcn_mfma_f32_16x16x32_bf16(
                    afr[m], bfr[nn], acc[m][nn], 0, 0, 0);
        __builtin_amdgcn_s_setprio(0);
        if (s < 7)
            *(bf16x8*)(smem + 49152 + (cur ^ 1) * 4096 + a_woff) = cvt8(v0, v1);
        __syncthreads();
    }

    // epilogue: y cols (0..127) -> fp8 region; z cols (128..383) -> bf16 region
    unsigned char* Cs8 = (unsigned char*)smem;     // [64][144] fp8
    bf16* Csz = (bf16*)(smem + 9216);              // [64][264] bf16
    #pragma unroll
    for (int m = 0; m < 4; m++) {
        #pragma unroll
        for (int nn = 0; nn < 6; nn++) {
            int col = wv * 96 + nn * 16 + f_l15;
            int r0 = m * 16 + (f_kg << 2);
            if (col < 128) {
                #pragma unroll
                for (int j = 0; j < 4; j++)
                    Cs8[(r0 + j) * 144 + col] = f32_fp8(acc[m][nn][j]);
            } else {
                #pragma unroll
                for (int j = 0; j < 4; j++)
                    Csz[(r0 + j) * 264 + (col - 128)] = (bf16)acc[m][nn][j];
            }
        }
    }
    __syncthreads();

    // y store: 64 rows x 128B fp8
    {
        #pragma unroll
        for (int h = 0; h < 2; h++) {
            int idx = h * 256 + t;
            int r = idx >> 3, ch = idx & 7;
            int gr = node0 + r;
            if (gr < n) {
                uint4 v = *(const uint4*)&Cs8[r * 144 + ch * 16];
                *(uint4*)&yq[(size_t)gr * 128 + ch * 16] = v;
            }
        }
    }
    // z store: 64 rows x 512B bf16
    {
        int r = t >> 2;
        int gr = node0 + r;
        if (gr < n) {
            #pragma unroll
            for (int u = 0; u < 8; u++) {
                int c = (t & 3) * 8 + u * 32;
                uint4 v = *(const uint4*)&Csz[r * 264 + c];
                *(uint4*)&z[(size_t)gr * 2 * HDIM + c] = v;
            }
        }
    }
}

// ---------- fused gather + epilogue: one wave per node, fp8 rows, 4B/lane ----------
__global__ __launch_bounds__(256) void k_gather(
    const unsigned char* __restrict__ yq, const bf16* __restrict__ z,
    const int* __restrict__ off, const int* __restrict__ cnt, const int* __restrict__ sidx,
    const float* __restrict__ bl, const float* __restrict__ bres,
    const float* __restrict__ wscore, const float* __restrict__ bscore,
    const float* __restrict__ wcrit, const float* __restrict__ bcrit,
    const float* __restrict__ rrs, const float* __restrict__ palpha,
    int n, float* __restrict__ outF, float* __restrict__ outL)
{
    __shared__ bf16 wsb[11 * 128];
    int t = threadIdx.x;
    for (int i = t; i < 11 * 128; i += 256) {
        int q = i >> 7, c = i & 127;
        wsb[i] = (bf16)((q == 0) ? wscore[c] : wcrit[(size_t)(q - 1) * HDIM + c]);
    }
    __syncthreads();

    int node = blockIdx.x * 4 + (t >> 6);
    if (node >= n) return;
    int lane = t & 63, r2 = lane >> 5, c32 = lane & 31;

    // node-local loads issued early (hide under gather loop)
    uint2 zr = *(const uint2*)&z[(size_t)node * 2 * HDIM + c32 * 4];
    uint2 zs = *(const uint2*)&z[(size_t)node * 2 * HDIM + HDIM + c32 * 4];
    float4 blv = *(const float4*)&bl[c32 * 4];
    float4 brv = *(const float4*)&bres[c32 * 4];

    const unsigned char* ybase = yq + c32 * 4;
    int beg = off[node], len = cnt[node];
    const int* sp = sidx + beg;

    float a0 = 0.f, a1 = 0.f, a2 = 0.f, a3 = 0.f;
    int e = 0;
    for (; e + 8 <= len; e += 8) {
        int i0 = sp[e + r2];
        int i1 = sp[e + 2 + r2];
        int i2 = sp[e + 4 + r2];
        int i3 = sp[e + 6 + r2];
        int v0 = *(const int*)(ybase + ((size_t)(unsigned)i0 << 7));
        int v1 = *(const int*)(ybase + ((size_t)(unsigned)i1 << 7));
        int v2 = *(const int*)(ybase + ((size_t)(unsigned)i2 << 7));
        int v3 = *(const int*)(ybase + ((size_t)(unsigned)i3 << 7));
        a0 += __builtin_amdgcn_cvt_f32_fp8(v0, 0) + __builtin_amdgcn_cvt_f32_fp8(v1, 0)
            + __builtin_amdgcn_cvt_f32_fp8(v2, 0) + __builtin_amdgcn_cvt_f32_fp8(v3, 0);
        a1 += __builtin_amdgcn_cvt_f32_fp8(v0, 1) + __builtin_amdgcn_cvt_f32_fp8(v1, 1)
            + __builtin_amdgcn_cvt_f32_fp8(v2, 1) + __builtin_amdgcn_cvt_f32_fp8(v3, 1);
        a2 += __builtin_amdgcn_cvt_f32_fp8(v0, 2) + __builtin_amdgcn_cvt_f32_fp8(v1, 2)
            + __builtin_amdgcn_cvt_f32_fp8(v2, 2) + __builtin_amdgcn_cvt_f32_fp8(v3, 2);
        a3 += __builtin_amdgcn_cvt_f32_fp8(v0, 3) + __builtin_amdgcn_cvt_f32_fp8(v1, 3)
            + __builtin_amdgcn_cvt_f32_fp8(v2, 3) + __builtin_amdgcn_cvt_f32_fp8(v3, 3);
    }
    for (; e < len; e += 2) {
        int slot = e + r2;
        int ii = sp[slot < len ? slot : len - 1];
        int v = *(const int*)(ybase + ((size_t)(unsigned)ii << 7));
        if (slot < len) {
            a0 += __builtin_amdgcn_cvt_f32_fp8(v, 0);
            a1 += __builtin_amdgcn_cvt_f32_fp8(v, 1);
            a2 += __builtin_amdgcn_cvt_f32_fp8(v, 2);
            a3 += __builtin_amdgcn_cvt_f32_fp8(v, 3);
        }
    }
    a0 += __shfl_xor(a0, 32, 64);
    a1 += __shfl_xor(a1, 32, 64);
    a2 += __shfl_xor(a2, 32, 64);
    a3 += __shfl_xor(a3, 32, 64);
    float inv = 1.f / fmaxf((float)len, 1.f);

    float h0 = fmaxf(a0 * inv + blv.x + bflo(zr.x), 0.f) + bflo(zs.x) + brv.x;
    float h1 = fmaxf(a1 * inv + blv.y + bfhi(zr.x), 0.f) + bfhi(zs.x) + brv.y;
    float h2 = fmaxf(a2 * inv + blv.z + bflo(zr.y), 0.f) + bflo(zs.y) + brv.z;
    float h3 = fmaxf(a3 * inv + blv.w + bfhi(zr.y), 0.f) + bfhi(zs.y) + brv.w;

    // split epilogue: half r2=0 handles q=0..5, half r2=1 handles q=6..10
    float p[6];
    #pragma unroll
    for (int qq = 0; qq < 6; qq++) {
        int q = r2 * 6 + qq;
        float s = 0.f;
        if (q < 11) {
            uint2 w = *(const uint2*)&wsb[q * 128 + c32 * 4];
            s = h0 * bflo(w.x) + h1 * bfhi(w.x) + h2 * bflo(w.y) + h3 * bfhi(w.y);
        }
        #pragma unroll
        for (int d = 1; d < 32; d <<= 1)
            s += __shfl_xor(s, d, 64);
        p[qq] = s;
    }
    if ((lane & 31) == 0) {
        if (r2 == 0) {
            float al = palpha[0];
            float aa = 1.f / (1.f + expf(-al));
            outF[node] = aa * rrs[node] + (1.f - aa) * (p[0] + bscore[0]);
            #pragma unroll
            for (int qq = 1; qq < 6; qq++)
                outL[(size_t)node * NCRIT + qq - 1] = p[qq] + bcrit[qq - 1];
        } else {
            #pragma unroll
            for (int qq = 0; qq < 5; qq++)
                outL[(size_t)node * NCRIT + 5 + qq] = p[qq] + bcrit[5 + qq];
        }
    }
}

extern "C" void kernel_launch(void* const* d_in, const int* in_sizes, int n_in,
                              void* d_out, int out_size, void* d_ws, size_t ws_size,
                              hipStream_t stream) {
    const float* x      = (const float*)d_in[0];
    const int*   ei     = (const int*)d_in[1];
    const float* rrs    = (const float*)d_in[2];
    const float* Wl     = (const float*)d_in[3];
    const float* bl     = (const float*)d_in[4];
    const float* Wr     = (const float*)d_in[5];
    const float* Wres   = (const float*)d_in[6];
    const float* bres   = (const float*)d_in[7];
    const float* wscore = (const float*)d_in[8];
    const float* bscore = (const float*)d_in[9];
    const float* wcrit  = (const float*)d_in[10];
    const float* bcrit  = (const float*)d_in[11];
    const float* alpha  = (const float*)d_in[12];

    int N = in_sizes[0] / DIN;
    int E = in_sizes[1] / 2;
    const int* srcv = ei;
    const int* dstv = ei + E;

    char* p = (char*)d_ws;
    size_t cntPad = alignup((size_t)N * 4, 256);
    int* cnt   = (int*)p; p += cntPad;
    int* total = (int*)p; p += 256;
    int* off   = (int*)p; p += alignup((size_t)N * 4, 256);
    int* epos  = (int*)p; p += alignup((size_t)E * 4, 256);
    int* sidx  = (int*)p; p += alignup((size_t)E * 4, 256);
    bf16* Wcat = (bf16*)p; p += alignup((size_t)384 * DIN * 2, 256);
    unsigned char* yq = (unsigned char*)p; p += alignup((size_t)N * HDIM, 256);
    bf16* z    = (bf16*)p; p += alignup((size_t)N * 2 * HDIM * 2, 256);

    // single memset covers cnt + total (adjacent)
    hipMemsetAsync(cnt, 0, cntPad + 256, stream);

    k_hist<<<(E + 255) / 256, 256, 0, stream>>>(dstv, E, cnt, epos);
    int nAllocBlocks = (N + 255) / 256;
    k_allocw<<<nAllocBlocks + 96, 256, 0, stream>>>(cnt, N, off, total, nAllocBlocks,
                                                    Wl, Wr, Wres, Wcat);
    k_scatter<<<(E + 255) / 256, 256, 0, stream>>>(srcv, dstv, epos, E, off, sidx);

    k_gemm<<<(N + 63) / 64, 256, 0, stream>>>(x, Wcat, N, yq, z);

    float* outF = (float*)d_out;
    float* outL = outF + N;
    k_gather<<<(N + 3) / 4, 256, 0, stream>>>(yq, z, off, cnt, sidx, bl, bres,
                                              wscore, bscore, wcrit, bcrit,
                                              rrs, alpha, N, outF, outL);
}